// Round 1
// baseline (341.700 us; speedup 1.0000x reference)
//
#include <hip/hip_runtime.h>

// Problem constants (from reference):
//   x: (160,128,48,48) f32, vth: (160,3) f32, mask_rand: (160,48,48) f32
//   TIME_STEP=5, bs=32, TAU=0.5, A=1.0 (step threshold at 0), LAYER=1 -> vth[:,0]
//   DropBlock: gamma = 0.2/49, 7x7 stride-1 SAME max-pool, bm = 1 - pooled
constexpr int N_   = 160;
constexpr int C_   = 128;
constexpr int H_   = 48;
constexpr int W_   = 48;
constexpr int T_   = 5;
constexpr int BS_  = 32;              // batch per time step
constexpr int HW_  = H_ * W_;         // 2304
constexpr int HW4_ = HW_ / 4;         // 576 (float4 units)
constexpr int CHW_ = C_ * HW_;        // 294912

// Kernel 1: DropBlock mask. One block per image n.
// bm[n,h,w] = 1 - max_{|dh|<=3,|dw|<=3, in-bounds} (mask_rand[n,h+dh,w+dw] < gamma)
__global__ __launch_bounds__(256) void block_mask_k(const float* __restrict__ mr,
                                                    float* __restrict__ bm) {
    const int n = blockIdx.x;
    __shared__ float s[HW_];
    const float* src = mr + (size_t)n * HW_;
    constexpr float GAMMA = 0.2f / 49.0f;
    for (int i = threadIdx.x; i < HW_; i += blockDim.x)
        s[i] = (src[i] < GAMMA) ? 1.0f : 0.0f;
    __syncthreads();
    float* dst = bm + (size_t)n * HW_;
    for (int i = threadIdx.x; i < HW_; i += blockDim.x) {
        const int h = i / W_, w = i % W_;
        const int h0 = (h - 3 < 0) ? 0 : h - 3;
        const int h1 = (h + 3 > H_ - 1) ? H_ - 1 : h + 3;
        const int w0 = (w - 3 < 0) ? 0 : w - 3;
        const int w1 = (w + 3 > W_ - 1) ? W_ - 1 : w + 3;
        float m = 0.0f;
        for (int hh = h0; hh <= h1; ++hh)
            for (int ww = w0; ww <= w1; ++ww)
                m = fmaxf(m, s[hh * W_ + ww]);
        dst[i] = 1.0f - m;
    }
}

// Kernel 2: LIF recurrence. One thread owns one (b, c, 4xhw) element group;
// u-state lives in registers across the unrolled t loop.
// u_new = (u_old >= v ? 0 : 0.5*u_old) + x_t ;  out_t = (u_new >= v) ? bm_t : 0
__global__ __launch_bounds__(256) void lif_k(const float* __restrict__ x,
                                             const float* __restrict__ vth,
                                             const float* __restrict__ bm,
                                             float* __restrict__ out) {
    const int tid = blockIdx.x * blockDim.x + threadIdx.x;
    const int hw4 = tid % HW4_;
    const int bc  = tid / HW4_;
    const int c   = bc % C_;
    const int b   = bc / C_;
    if (b >= BS_) return;

    float ux = 0.0f, uy = 0.0f, uz = 0.0f, uw = 0.0f;

#pragma unroll
    for (int t = 0; t < T_; ++t) {
        const int n = t * BS_ + b;
        const float v = vth[(size_t)n * 3];  // LAYER-1 == 0; wave-uniform broadcast
        const size_t xoff = (size_t)n * CHW_ + (size_t)c * HW_;
        const float4 xt = reinterpret_cast<const float4*>(x + xoff)[hw4];
        const float4 bt = reinterpret_cast<const float4*>(bm + (size_t)n * HW_)[hw4];

        ux = (ux >= v ? 0.0f : 0.5f * ux) + xt.x;
        uy = (uy >= v ? 0.0f : 0.5f * uy) + xt.y;
        uz = (uz >= v ? 0.0f : 0.5f * uz) + xt.z;
        uw = (uw >= v ? 0.0f : 0.5f * uw) + xt.w;

        float4 o;
        o.x = (ux >= v) ? bt.x : 0.0f;
        o.y = (uy >= v) ? bt.y : 0.0f;
        o.z = (uz >= v) ? bt.z : 0.0f;
        o.w = (uw >= v) ? bt.w : 0.0f;
        reinterpret_cast<float4*>(out + xoff)[hw4] = o;
    }
}

extern "C" void kernel_launch(void* const* d_in, const int* in_sizes, int n_in,
                              void* d_out, int out_size, void* d_ws, size_t ws_size,
                              hipStream_t stream) {
    const float* x    = (const float*)d_in[0];
    const float* vth  = (const float*)d_in[1];
    const float* mr   = (const float*)d_in[2];
    float* out = (float*)d_out;
    float* bm  = (float*)d_ws;  // N_*HW_ floats = 1.47 MB scratch

    block_mask_k<<<N_, 256, 0, stream>>>(mr, bm);

    const int total_threads = BS_ * C_ * HW4_;  // 2,359,296
    const int block = 256;
    const int grid = (total_threads + block - 1) / block;  // 9216
    lif_k<<<grid, block, 0, stream>>>(x, vth, bm, out);
}

// Round 3
// 336.019 us; speedup vs baseline: 1.0169x; 1.0169x over previous
//
#include <hip/hip_runtime.h>

// Problem constants (from reference):
//   x: (160,128,48,48) f32, vth: (160,3) f32, mask_rand: (160,48,48) f32
//   TIME_STEP=5, bs=32, TAU=0.5, A=1.0 (step threshold at 0), LAYER=1 -> vth[:,0]
//   DropBlock: gamma = 0.2/49, 7x7 stride-1 SAME max-pool, bm = 1 - pooled
constexpr int N_   = 160;
constexpr int C_   = 128;
constexpr int H_   = 48;
constexpr int W_   = 48;
constexpr int T_   = 5;
constexpr int BS_  = 32;              // batch per time step
constexpr int HW_  = H_ * W_;         // 2304
constexpr int HW4_ = HW_ / 4;         // 576 (float4 units) = exactly 9 waves -> v is wave-uniform
constexpr int CHW_ = C_ * HW_;        // 294912

// Native clang vector type — accepted by __builtin_nontemporal_{load,store}
// (HIP_vector_type float4 is a struct and is rejected).
typedef float f32x4 __attribute__((ext_vector_type(4)));

// Kernel 1: DropBlock mask. One block per image n.
// bm[n,h,w] = 1 - max_{|dh|<=3,|dw|<=3, in-bounds} (mask_rand[n,h+dh,w+dw] < gamma)
__global__ __launch_bounds__(256) void block_mask_k(const float* __restrict__ mr,
                                                    float* __restrict__ bm) {
    const int n = blockIdx.x;
    __shared__ float s[HW_];
    const float* src = mr + (size_t)n * HW_;
    constexpr float GAMMA = 0.2f / 49.0f;
    for (int i = threadIdx.x; i < HW_; i += blockDim.x)
        s[i] = (src[i] < GAMMA) ? 1.0f : 0.0f;
    __syncthreads();
    float* dst = bm + (size_t)n * HW_;
    for (int i = threadIdx.x; i < HW_; i += blockDim.x) {
        const int h = i / W_, w = i % W_;
        const int h0 = (h - 3 < 0) ? 0 : h - 3;
        const int h1 = (h + 3 > H_ - 1) ? H_ - 1 : h + 3;
        const int w0 = (w - 3 < 0) ? 0 : w - 3;
        const int w1 = (w + 3 > W_ - 1) ? W_ - 1 : w + 3;
        float m = 0.0f;
        for (int hh = h0; hh <= h1; ++hh)
            for (int ww = w0; ww <= w1; ++ww)
                m = fmaxf(m, s[hh * W_ + ww]);
        dst[i] = 1.0f - m;
    }
}

// Kernel 2: LIF recurrence. One thread owns one (b, c, 4xhw) group; u-state in
// registers across the unrolled t loop. x/out are streamed (non-temporal, zero
// reuse); bm stays in the normal cache path (reused 128x across channels).
// u_new = (u_old >= v ? 0 : 0.5*u_old) + x_t ;  out_t = (u_new >= v) ? bm_t : 0
__global__ __launch_bounds__(256) void lif_k(const float* __restrict__ x,
                                             const float* __restrict__ vth,
                                             const float* __restrict__ bm,
                                             float* __restrict__ out) {
    const int tid = blockIdx.x * blockDim.x + threadIdx.x;
    const int hw4 = tid % HW4_;
    const int bc  = tid / HW4_;
    const int c   = bc % C_;
    const int b   = bc / C_;

    const size_t base = (size_t)b * CHW_ + (size_t)c * HW_ + (size_t)hw4 * 4;
    constexpr size_t T_STRIDE = (size_t)BS_ * CHW_;   // elements between time steps

    float ux = 0.0f, uy = 0.0f, uz = 0.0f, uw = 0.0f;

#pragma unroll
    for (int t = 0; t < T_; ++t) {
        const int n = t * BS_ + b;
        const float v = vth[(size_t)n * 3];  // LAYER-1 == 0; wave-uniform
        const f32x4 xt = __builtin_nontemporal_load(
            reinterpret_cast<const f32x4*>(x + base + (size_t)t * T_STRIDE));
        const f32x4 bt = reinterpret_cast<const f32x4*>(bm + (size_t)n * HW_)[hw4];

        ux = (ux >= v ? 0.0f : 0.5f * ux) + xt.x;
        uy = (uy >= v ? 0.0f : 0.5f * uy) + xt.y;
        uz = (uz >= v ? 0.0f : 0.5f * uz) + xt.z;
        uw = (uw >= v ? 0.0f : 0.5f * uw) + xt.w;

        f32x4 o;
        o.x = (ux >= v) ? bt.x : 0.0f;
        o.y = (uy >= v) ? bt.y : 0.0f;
        o.z = (uz >= v) ? bt.z : 0.0f;
        o.w = (uw >= v) ? bt.w : 0.0f;
        __builtin_nontemporal_store(
            o, reinterpret_cast<f32x4*>(out + base + (size_t)t * T_STRIDE));
    }
}

extern "C" void kernel_launch(void* const* d_in, const int* in_sizes, int n_in,
                              void* d_out, int out_size, void* d_ws, size_t ws_size,
                              hipStream_t stream) {
    const float* x    = (const float*)d_in[0];
    const float* vth  = (const float*)d_in[1];
    const float* mr   = (const float*)d_in[2];
    float* out = (float*)d_out;
    float* bm  = (float*)d_ws;  // N_*HW_ floats = 1.47 MB scratch

    block_mask_k<<<N_, 256, 0, stream>>>(mr, bm);

    const int total_threads = BS_ * C_ * HW4_;  // 2,359,296
    const int block = 256;
    const int grid = total_threads / block;     // 9216, exact
    lif_k<<<grid, block, 0, stream>>>(x, vth, bm, out);
}

// Round 4
// 313.054 us; speedup vs baseline: 1.0915x; 1.0734x over previous
//
#include <hip/hip_runtime.h>

// Problem constants (from reference):
//   x: (160,128,48,48) f32, vth: (160,3) f32, mask_rand: (160,48,48) f32
//   TIME_STEP=5, bs=32, TAU=0.5, A=1.0 (step threshold at 0), LAYER=1 -> vth[:,0]
//   DropBlock: gamma = 0.2/49, 7x7 stride-1 SAME max-pool, bm = 1 - pooled
constexpr int N_   = 160;
constexpr int C_   = 128;
constexpr int H_   = 48;
constexpr int W_   = 48;
constexpr int T_   = 5;
constexpr int BS_  = 32;              // batch per time step
constexpr int HW_  = H_ * W_;         // 2304
constexpr int HW4_ = HW_ / 4;         // 576 (float4 units) = exactly 9 waves -> v is wave-uniform
constexpr int CHW_ = C_ * HW_;        // 294912

typedef float f32x4 __attribute__((ext_vector_type(4)));

// Kernel 1: DropBlock mask, separable max-pool, one block per (n, 8-row strip).
// 960 blocks (vs 160) for CU coverage; 7+7 ops/output instead of 49.
constexpr int STRIP_ROWS = 8;
constexpr int STRIPS     = H_ / STRIP_ROWS;  // 6
constexpr int HALO_ROWS  = STRIP_ROWS + 6;   // 14 (3-row halo each side)

__global__ __launch_bounds__(256) void block_mask_k(const float* __restrict__ mr,
                                                    float* __restrict__ bm) {
    const int n  = blockIdx.x / STRIPS;
    const int s  = blockIdx.x % STRIPS;
    const int r0 = s * STRIP_ROWS;
    constexpr float GAMMA = 0.2f / 49.0f;

    __shared__ float seed[HALO_ROWS][W_];   // binarized seeds (OOB rows -> 0)
    __shared__ float hmax[HALO_ROWS][W_];   // 7-wide horizontal max

    const float* src = mr + (size_t)n * HW_;

    // Stage A: load + binarize seeds for rows [r0-3, r0+10], clip to 0 outside image
    for (int i = threadIdx.x; i < HALO_ROWS * W_; i += 256) {
        const int lr = i / W_, w = i % W_;
        const int gr = r0 - 3 + lr;
        float v = 0.0f;
        if (gr >= 0 && gr < H_) v = (src[gr * W_ + w] < GAMMA) ? 1.0f : 0.0f;
        seed[lr][w] = v;
    }
    __syncthreads();

    // Stage B: horizontal 7-window max (OOB columns contribute 0 == clamped max)
    for (int i = threadIdx.x; i < HALO_ROWS * W_; i += 256) {
        const int lr = i / W_, w = i % W_;
        float m = 0.0f;
#pragma unroll
        for (int dw = -3; dw <= 3; ++dw) {
            const int ww = w + dw;
            if (ww >= 0 && ww < W_) m = fmaxf(m, seed[lr][ww]);
        }
        hmax[lr][w] = m;
    }
    __syncthreads();

    // Stage C: vertical 7-window max, write bm rows [r0, r0+8)
    float* dst = bm + (size_t)n * HW_;
    for (int i = threadIdx.x; i < STRIP_ROWS * W_; i += 256) {
        const int lh = i / W_, w = i % W_;
        float m = 0.0f;
#pragma unroll
        for (int dr = 0; dr < 7; ++dr)
            m = fmaxf(m, hmax[lh + dr][w]);
        dst[(r0 + lh) * W_ + w] = 1.0f - m;
    }
}

// Kernel 2: LIF recurrence. One thread owns one (b, c, 4xhw) group; u-state in
// registers across the unrolled t loop. x/out are streamed (non-temporal, zero
// reuse); bm stays in the normal cache path (reused 128x across channels).
// u_new = (u_old >= v ? 0 : 0.5*u_old) + x_t ;  out_t = (u_new >= v) ? bm_t : 0
__global__ __launch_bounds__(256) void lif_k(const float* __restrict__ x,
                                             const float* __restrict__ vth,
                                             const float* __restrict__ bm,
                                             float* __restrict__ out) {
    const int tid = blockIdx.x * blockDim.x + threadIdx.x;
    const int hw4 = tid % HW4_;
    const int bc  = tid / HW4_;
    const int c   = bc % C_;
    const int b   = bc / C_;

    const size_t base = (size_t)b * CHW_ + (size_t)c * HW_ + (size_t)hw4 * 4;
    constexpr size_t T_STRIDE = (size_t)BS_ * CHW_;   // elements between time steps

    float ux = 0.0f, uy = 0.0f, uz = 0.0f, uw = 0.0f;

#pragma unroll
    for (int t = 0; t < T_; ++t) {
        const int n = t * BS_ + b;
        const float v = vth[(size_t)n * 3];  // LAYER-1 == 0; wave-uniform
        const f32x4 xt = __builtin_nontemporal_load(
            reinterpret_cast<const f32x4*>(x + base + (size_t)t * T_STRIDE));
        const f32x4 bt = reinterpret_cast<const f32x4*>(bm + (size_t)n * HW_)[hw4];

        ux = (ux >= v ? 0.0f : 0.5f * ux) + xt.x;
        uy = (uy >= v ? 0.0f : 0.5f * uy) + xt.y;
        uz = (uz >= v ? 0.0f : 0.5f * uz) + xt.z;
        uw = (uw >= v ? 0.0f : 0.5f * uw) + xt.w;

        f32x4 o;
        o.x = (ux >= v) ? bt.x : 0.0f;
        o.y = (uy >= v) ? bt.y : 0.0f;
        o.z = (uz >= v) ? bt.z : 0.0f;
        o.w = (uw >= v) ? bt.w : 0.0f;
        __builtin_nontemporal_store(
            o, reinterpret_cast<f32x4*>(out + base + (size_t)t * T_STRIDE));
    }
}

extern "C" void kernel_launch(void* const* d_in, const int* in_sizes, int n_in,
                              void* d_out, int out_size, void* d_ws, size_t ws_size,
                              hipStream_t stream) {
    const float* x    = (const float*)d_in[0];
    const float* vth  = (const float*)d_in[1];
    const float* mr   = (const float*)d_in[2];
    float* out = (float*)d_out;
    float* bm  = (float*)d_ws;  // N_*HW_ floats = 1.47 MB scratch

    block_mask_k<<<N_ * STRIPS, 256, 0, stream>>>(mr, bm);

    const int total_threads = BS_ * C_ * HW4_;  // 2,359,296
    const int block = 256;
    const int grid = total_threads / block;     // 9216, exact
    lif_k<<<grid, block, 0, stream>>>(x, vth, bm, out);
}